// Round 4
// baseline (425.079 us; speedup 1.0000x reference)
//
#include <hip/hip_runtime.h>

// Actor_attf_single — MI355X (gfx950)
// R13 = R12 resubmitted verbatim (R3 bench was an infra failure: "MI355X
// container failed twice" — no counters, hypothesis untested).
// Ledger:
//   R8  329us: 2-entity batch, VGPR 76, no spills
//   R9  352us: role-split TLP — regressed; TLP is not the limiter
//   R10 1445us: LDS weights -> ds_read VGPR explosion -> 540MB spill traffic
//   R11 289us: 3/4-entity batch BUT __launch_bounds__(256,4) let the
//       allocator squeeze to VGPR=64 and spill (~20MB extra WRITE_SIZE,
//       scratch reloads inside the softmax epilogue critical path)
// R12/R13 change (single variable): __launch_bounds__(256, 2) -> VGPR cap
// 256, so enc[3][16]/enc[4][16] stay in registers. Success criterion:
// WRITE_SIZE back to ~2MB, VGPR ~110-150. Math bitwise-identical to R11
// (absmax must stay 0.00390625).
//   - weights stay on the s_load/SGPR path (zero VGPR cost)
//   - batch 3 for "other" (5 passes/15 entities), 4 for "food" (4 passes/16)

#define LN_EPS 1e-5f

struct Weights {
  const float* __restrict__ en_W1; const float* __restrict__ en_b1;
  const float* __restrict__ en_W2; const float* __restrict__ en_b2;
  const float* __restrict__ oa_W1; const float* __restrict__ oa_b1;
  const float* __restrict__ oa_W2; const float* __restrict__ oa_b2;
  const float* __restrict__ go_W1; const float* __restrict__ go_b1;
  const float* __restrict__ go_W2; const float* __restrict__ go_b2;
  const float* __restrict__ oa_g;  const float* __restrict__ oa_b;
  const float* __restrict__ go_g;  const float* __restrict__ go_b;
  const float* __restrict__ a_W1;  const float* __restrict__ a_b1;
  const float* __restrict__ a_W2;  const float* __restrict__ a_b2;
  const float* __restrict__ a_W3;  const float* __restrict__ a_b3;
};

__device__ __forceinline__ float2 ld2(const float* __restrict__ p) {
  return *reinterpret_cast<const float2*>(p);
}

__global__ __launch_bounds__(256, 2)
void actor_fwd(const float* __restrict__ s_input, Weights W,
               float* __restrict__ out, int bsz) {
  const int lane = threadIdx.x & 63;
  const int wv   = threadIdx.x >> 6;        // 0..3, independent waves
  int row = blockIdx.x * 256 + wv * 64 + lane;
  row = min(row, bsz - 1);
  const float* __restrict__ srow = s_input + (size_t)row * 96;

  // ---------------- self encoder: fused 4 -> 32 -> 16, relu ----------------
  float self_out[16];
  {
    float2 p01 = ld2(srow + 0);
    float2 p23 = ld2(srow + 2);
#pragma unroll
    for (int d = 0; d < 16; ++d) self_out[d] = W.en_b2[d];
#pragma unroll
    for (int j = 0; j < 32; ++j) {
      float h = W.en_b1[j];
      h = fmaf(p01.x, W.en_W1[ 0 + j], h);
      h = fmaf(p01.y, W.en_W1[32 + j], h);
      h = fmaf(p23.x, W.en_W1[64 + j], h);
      h = fmaf(p23.y, W.en_W1[96 + j], h);
      h = fmaxf(h, 0.f);
#pragma unroll
      for (int d = 0; d < 16; ++d)
        self_out[d] = fmaf(h, W.en_W2[j*16 + d], self_out[d]);
    }
#pragma unroll
    for (int d = 0; d < 16; ++d) self_out[d] = fmaxf(self_out[d], 0.f);
  }

  // ------- other agents: 15 x (4->32->16), batches of 3 ------------------
  float other_pool[16];
  {
    float m = -3.0e38f, l = 0.f, acc[16];
#pragma unroll
    for (int d = 0; d < 16; ++d) acc[d] = 0.f;

#pragma unroll 1
    for (int k0 = 0; k0 < 15; k0 += 3) {
      float2 i01[3], i23[3];
#pragma unroll
      for (int e = 0; e < 3; ++e) {
        i01[e] = ld2(srow + 4  + 2*(k0 + e));
        i23[e] = ld2(srow + 34 + 2*(k0 + e));
      }
      float enc[3][16];
#pragma unroll
      for (int d = 0; d < 16; ++d) {
        float b2 = W.oa_b2[d];
#pragma unroll
        for (int e = 0; e < 3; ++e) enc[e][d] = b2;
      }
#pragma unroll
      for (int j = 0; j < 32; ++j) {
        float w0 = W.oa_W1[ 0 + j], w1 = W.oa_W1[32 + j];
        float w2 = W.oa_W1[64 + j], w3 = W.oa_W1[96 + j];
        float b1 = W.oa_b1[j];
        float h[3];
#pragma unroll
        for (int e = 0; e < 3; ++e) {
          float t = fmaf(i01[e].x, w0, b1);
          t = fmaf(i01[e].y, w1, t);
          t = fmaf(i23[e].x, w2, t);
          t = fmaf(i23[e].y, w3, t);
          h[e] = fmaxf(t, 0.f);
        }
#pragma unroll
        for (int d = 0; d < 16; ++d) {
          float w = W.oa_W2[j*16 + d];
#pragma unroll
          for (int e = 0; e < 3; ++e) enc[e][d] = fmaf(h[e], w, enc[e][d]);
        }
      }
      // per-entity epilogue, strictly in entity order (bitwise == R8)
#pragma unroll
      for (int e = 0; e < 3; ++e) {
        float s = 0.f;
#pragma unroll
        for (int d = 0; d < 16; ++d) {
          enc[e][d] = fmaxf(enc[e][d], 0.f);
          s = fmaf(self_out[d], enc[e][d], s);
        }
        s *= 0.25f;
        float mn = fmaxf(m, s);
        float alpha = __expf(m - mn), w = __expf(s - mn);
        l = fmaf(l, alpha, w);
#pragma unroll
        for (int d = 0; d < 16; ++d) acc[d] = fmaf(acc[d], alpha, w * enc[e][d]);
        m = mn;
      }
    }

    float inv = 1.f / l;
    float mu = 0.f;
#pragma unroll
    for (int d = 0; d < 16; ++d) { acc[d] *= inv; mu += acc[d]; }
    mu *= (1.f / 16.f);
    float var = 0.f;
#pragma unroll
    for (int d = 0; d < 16; ++d) { float x = acc[d] - mu; var = fmaf(x, x, var); }
    var *= (1.f / 16.f);
    float rstd = rsqrtf(var + LN_EPS);
#pragma unroll
    for (int d = 0; d < 16; ++d)
      other_pool[d] = fmaxf(fmaf((acc[d] - mu) * rstd, W.oa_g[d], W.oa_b[d]), 0.f);
  }

  // ------- food: 16 x (2->32->16), batches of 4 --------------------------
  float food_pool[16];
  {
    float m = -3.0e38f, l = 0.f, acc[16];
#pragma unroll
    for (int d = 0; d < 16; ++d) acc[d] = 0.f;

#pragma unroll 1
    for (int k0 = 0; k0 < 16; k0 += 4) {
      float2 fi[4];
#pragma unroll
      for (int e = 0; e < 4; ++e) fi[e] = ld2(srow + 64 + 2*(k0 + e));
      float enc[4][16];
#pragma unroll
      for (int d = 0; d < 16; ++d) {
        float b2 = W.go_b2[d];
#pragma unroll
        for (int e = 0; e < 4; ++e) enc[e][d] = b2;
      }
#pragma unroll
      for (int j = 0; j < 32; ++j) {
        float w0 = W.go_W1[0 + j], w1 = W.go_W1[32 + j];
        float b1 = W.go_b1[j];
        float h[4];
#pragma unroll
        for (int e = 0; e < 4; ++e) {
          float t = fmaf(fi[e].x, w0, b1);
          t = fmaf(fi[e].y, w1, t);
          h[e] = fmaxf(t, 0.f);
        }
#pragma unroll
        for (int d = 0; d < 16; ++d) {
          float w = W.go_W2[j*16 + d];
#pragma unroll
          for (int e = 0; e < 4; ++e) enc[e][d] = fmaf(h[e], w, enc[e][d]);
        }
      }
      // per-entity epilogue, strictly in entity order (bitwise == R8)
#pragma unroll
      for (int e = 0; e < 4; ++e) {
        float s = 0.f;
#pragma unroll
        for (int d = 0; d < 16; ++d) {
          enc[e][d] = fmaxf(enc[e][d], 0.f);
          s = fmaf(self_out[d], enc[e][d], s);
        }
        s *= 0.25f;
        float mn = fmaxf(m, s);
        float alpha = __expf(m - mn), w = __expf(s - mn);
        l = fmaf(l, alpha, w);
#pragma unroll
        for (int d = 0; d < 16; ++d) acc[d] = fmaf(acc[d], alpha, w * enc[e][d]);
        m = mn;
      }
    }

    float inv = 1.f / l;
    float mu = 0.f;
#pragma unroll
    for (int d = 0; d < 16; ++d) { acc[d] *= inv; mu += acc[d]; }
    mu *= (1.f / 16.f);
    float var = 0.f;
#pragma unroll
    for (int d = 0; d < 16; ++d) { float x = acc[d] - mu; var = fmaf(x, x, var); }
    var *= (1.f / 16.f);
    float rstd = rsqrtf(var + LN_EPS);
#pragma unroll
    for (int d = 0; d < 16; ++d)
      food_pool[d] = fmaxf(fmaf((acc[d] - mu) * rstd, W.go_g[d], W.go_b[d]), 0.f);
  }

  // ------- action head: 48 -> 32 -> 32 -> 2 ------------------------------
  float h1[32];
#pragma unroll
  for (int j = 0; j < 32; ++j) h1[j] = W.a_b1[j];
#pragma unroll
  for (int c = 0; c < 16; ++c) {
    float v = self_out[c];
#pragma unroll
    for (int j = 0; j < 32; ++j) h1[j] = fmaf(v, W.a_W1[c*32 + j], h1[j]);
  }
#pragma unroll
  for (int c = 0; c < 16; ++c) {
    float v = food_pool[c];
#pragma unroll
    for (int j = 0; j < 32; ++j) h1[j] = fmaf(v, W.a_W1[(16 + c)*32 + j], h1[j]);
  }
#pragma unroll
  for (int c = 0; c < 16; ++c) {
    float v = other_pool[c];
#pragma unroll
    for (int j = 0; j < 32; ++j) h1[j] = fmaf(v, W.a_W1[(32 + c)*32 + j], h1[j]);
  }
#pragma unroll
  for (int j = 0; j < 32; ++j) h1[j] = fmaxf(h1[j], 0.01f * h1[j]);   // leaky

  float h2[32];
#pragma unroll
  for (int j = 0; j < 32; ++j) h2[j] = W.a_b2[j];
#pragma unroll
  for (int c = 0; c < 32; ++c) {
    float v = h1[c];
#pragma unroll
    for (int j = 0; j < 32; ++j) h2[j] = fmaf(v, W.a_W2[c*32 + j], h2[j]);
  }
#pragma unroll
  for (int j = 0; j < 32; ++j) h2[j] = fmaxf(h2[j], 0.01f * h2[j]);

  float o0 = W.a_b3[0], o1 = W.a_b3[1];
#pragma unroll
  for (int c = 0; c < 32; ++c) {
    o0 = fmaf(h2[c], W.a_W3[c*2 + 0], o0);
    o1 = fmaf(h2[c], W.a_W3[c*2 + 1], o1);
  }
  o0 = tanhf(o0);
  o1 = tanhf(o1);

  reinterpret_cast<float2*>(out)[row] = make_float2(o0, o1);
}

extern "C" void kernel_launch(void* const* d_in, const int* in_sizes, int n_in,
                              void* d_out, int out_size, void* d_ws, size_t ws_size,
                              hipStream_t stream) {
  const float* s_input = (const float*)d_in[0];
  Weights W;
  W.en_W1 = (const float*)d_in[1];  W.en_b1 = (const float*)d_in[2];
  W.en_W2 = (const float*)d_in[3];  W.en_b2 = (const float*)d_in[4];
  W.oa_W1 = (const float*)d_in[5];  W.oa_b1 = (const float*)d_in[6];
  W.oa_W2 = (const float*)d_in[7];  W.oa_b2 = (const float*)d_in[8];
  W.go_W1 = (const float*)d_in[9];  W.go_b1 = (const float*)d_in[10];
  W.go_W2 = (const float*)d_in[11]; W.go_b2 = (const float*)d_in[12];
  W.oa_g  = (const float*)d_in[13]; W.oa_b  = (const float*)d_in[14];
  W.go_g  = (const float*)d_in[15]; W.go_b  = (const float*)d_in[16];
  W.a_W1  = (const float*)d_in[17]; W.a_b1  = (const float*)d_in[18];
  W.a_W2  = (const float*)d_in[19]; W.a_b2  = (const float*)d_in[20];
  W.a_W3  = (const float*)d_in[21]; W.a_b3  = (const float*)d_in[22];

  const int bsz = in_sizes[0] / 96;          // 262144
  const int blocks = (bsz + 255) / 256;      // 256 rows per block, 4 waves
  actor_fwd<<<blocks, 256, 0, stream>>>(s_input, W, (float*)d_out, bsz);
}